// Round 8
// baseline (105.881 us; speedup 1.0000x reference)
//
#include <hip/hip_runtime.h>
#include <hip/hip_bf16.h>

#define D_DIM 256
#define TEMP 0.2f
// ZSCALE = sqrt(log2(e)/TEMP): fold 1/(T*ln2) into z so epilogue is exp2(acc)
#define ZSCALE 2.6857913f
#define TGRID 64           // N / 128 row/col tiles
#define NBLK 512           // 2 blocks per CU
#define NTILES 2080        // TGRID*(TGRID+1)/2 triangular tiles

typedef float f32x4 __attribute__((ext_vector_type(4)));
typedef unsigned long ulong_t;

typedef const __attribute__((address_space(1))) void* gptr_t;
typedef __attribute__((address_space(3))) void* lptr_t;

// ---------------- kernel 1: normalize + positives -> fp8 e4m3 ----------------
__global__ __launch_bounds__(256) void nt_normalize(
    const float* __restrict__ ei, const float* __restrict__ ej,
    unsigned char* __restrict__ z8, float* __restrict__ pos, int B) {
  int b = blockIdx.x;
  int d = threadIdx.x;
  float xi = ei[(size_t)b * D_DIM + d];
  float xj = ej[(size_t)b * D_DIM + d];
  float si = xi * xi, sj = xj * xj, sij = xi * xj;
  for (int off = 1; off < 64; off <<= 1) {
    si  += __shfl_xor(si, off);
    sj  += __shfl_xor(sj, off);
    sij += __shfl_xor(sij, off);
  }
  __shared__ float red[3][4];
  int wv = threadIdx.x >> 6, lane = threadIdx.x & 63;
  if (lane == 0) { red[0][wv] = si; red[1][wv] = sj; red[2][wv] = sij; }
  __syncthreads();
  si  = red[0][0] + red[0][1] + red[0][2] + red[0][3];
  sj  = red[1][0] + red[1][1] + red[1][2] + red[1][3];
  sij = red[2][0] + red[2][1] + red[2][2] + red[2][3];
  float ri = rsqrtf(si), rj = rsqrtf(sj);
  float zif = xi * ri * ZSCALE;
  float zjf = xj * rj * ZSCALE;
  // pack pairs (d, d+1) into one ushort of 2 fp8 bytes (HW RNE, OCP e4m3)
  float zih = __shfl_down(zif, 1);
  float zjh = __shfl_down(zjf, 1);
  if ((d & 1) == 0) {
    int pki = __builtin_amdgcn_cvt_pk_fp8_f32(zif, zih, 0, false);
    int pkj = __builtin_amdgcn_cvt_pk_fp8_f32(zjf, zjh, 0, false);
    ushort* zi_row = (ushort*)(z8 + (size_t)b * D_DIM);
    ushort* zj_row = (ushort*)(z8 + (size_t)(B + b) * D_DIM);
    zi_row[d >> 1] = (ushort)(pki & 0xffff);
    zj_row[d >> 1] = (ushort)(pkj & 0xffff);
  }
  if (threadIdx.x == 0) pos[b] = sij * ri * rj;
}

// ---------------- kernel 2: barrier-free triangular GEMM (fp8) --------------
// 512 threads = 8 waves (2 wave-rows x 4 wave-cols); wave tile 64 rows x 32
// cols. A panel (128 x K=256 fp8) in registers (af[8][4] ulong = 64 VGPR),
// staged via LDS only at rt transitions (2 barriers per ~4 tiles). B is
// STREAMED from global (L1/L2-resident z8) into registers: 16 x
// global_load_dwordx2 per tile per lane, immediate offsets off 2 base ptrs.
// The ct-sweep therefore has NO __syncthreads at all -- waves free-run, and
// one wave's loads/epilogue overlap other waves' MFMA (TLP, 2 blocks/CU).
// partial slots (256), R6-verified exact partition:
//   row-sums of (rt,ct) -> slot 4*ct+wc;  col-sums (rt<ct) -> 4*rt+2*wr+half.
__global__ __launch_bounds__(512, 4) void nt_gemm_rowsum(
    const unsigned char* __restrict__ z8, float* __restrict__ partial, int N) {
  // XCD-chunked bijective remap: consecutive logical blocks (sharing panels)
  // land on the same XCD's L2.
  int hw = blockIdx.x;
  int b = (hw & 7) * (NBLK / 8) + (hw >> 3);
  int s = (b * NTILES) / NBLK;
  int e = ((b + 1) * NTILES) / NBLK;

  // decode first tile index -> (rt, ct), lex order over ct>=rt
  int rem = s, rt = 0;
  while (rem >= TGRID - rt) { rem -= TGRID - rt; ++rt; }
  int ct = rt + rem;

  __shared__ __align__(16) unsigned char As[128 * 256];  // 32KB A-stage buffer

  int t = threadIdx.x, lane = t & 63, wv = t >> 6;
  int wr = wv >> 2, wc = wv & 3;    // 2 wave-rows x 4 wave-cols
  int g = lane >> 4;                // lane quad 0..3

  // Stage a 128x256 fp8 panel (32KB): 2048 16B chunks, 16 per 256B row.
  // XOR swizzle (byte ^= (row&7)<<4) via inverse-swizzled SOURCE (rule #21).
  auto STAGE = [&](int panel) {
#pragma unroll
    for (int p = 0; p < 4; ++p) {
      int chunk = p * 512 + t;          // 0..2047
      int row = chunk >> 4;             // 16 chunks per 256B row
      int c = chunk & 15;
      int cl = c ^ (row & 7);           // inverse swizzle on SOURCE
      const char* gsrc = (const char*)z8 + (size_t)(panel * 128 + row) * 256 + cl * 16;
      __builtin_amdgcn_global_load_lds((gptr_t)gsrc, (lptr_t)((char*)As + chunk * 16), 16, 0, 0);
    }
  };

  ulong_t af[8][4];                     // A frags [ks][m]: 64 rows x K=256
  auto READ_AF = [&]() {
#pragma unroll
    for (int ks = 0; ks < 8; ++ks)
#pragma unroll
      for (int m = 0; m < 4; ++m) {
        int r = wr * 64 + m * 16 + (lane & 15);
        int addr = ((r << 8) + ks * 32 + (g << 3)) ^ ((r & 7) << 4);
        af[ks][m] = *reinterpret_cast<const ulong_t*>((const char*)As + addr);
      }
  };

  int cur_rt = -1;

  for (int idx = s; idx < e; ++idx) {
    if (rt != cur_rt) {                 // uniform across the block
      __syncthreads();                  // everyone done with previous A buffer
      STAGE(rt);
      __syncthreads();                  // vmcnt drained: panel in LDS
      READ_AF();
      cur_rt = rt;
    }

    // ---- B stream base pointers for this tile (n=0 rows, n=1 rows) ----
    const unsigned char* b0 =
        z8 + (((size_t)(ct * 128 + wc * 32 + (lane & 15))) << 8) + (g << 3);
    const unsigned char* b1 = b0 + (16 << 8);   // +16 rows

    // ---- compute: acc = A_regs x B_stream over K=256 ----
    f32x4 acc[4][2];
#pragma unroll
    for (int m = 0; m < 4; ++m)
#pragma unroll
      for (int n = 0; n < 2; ++n) acc[m][n] = f32x4{0.f, 0.f, 0.f, 0.f};
#pragma unroll
    for (int ks = 0; ks < 8; ++ks) {
      ulong_t bf0 = *reinterpret_cast<const ulong_t*>(b0 + ks * 32);
      ulong_t bf1 = *reinterpret_cast<const ulong_t*>(b1 + ks * 32);
#pragma unroll
      for (int m = 0; m < 4; ++m) {
        acc[m][0] = __builtin_amdgcn_mfma_f32_16x16x32_fp8_fp8(
            (long)af[ks][m], (long)bf0, acc[m][0], 0, 0, 0);
        acc[m][1] = __builtin_amdgcn_mfma_f32_16x16x32_fp8_fp8(
            (long)af[ks][m], (long)bf1, acc[m][1], 0, 0, 0);
      }
    }

    // ---- epilogue (register-only): exp2, diag mask, row/col sums ----
    bool isdiag = (rt == ct);
    int rbase = rt * 128 + wr * 64;
    int cbase = ct * 128 + wc * 32 + (lane & 15);
#pragma unroll
    for (int m = 0; m < 4; ++m)
#pragma unroll
      for (int n = 0; n < 2; ++n)
#pragma unroll
        for (int j = 0; j < 4; ++j) {
          int rowg = rbase + m * 16 + g * 4 + j;
          int colg = cbase + n * 16;
          float ex = exp2f(acc[m][n][j]);
          acc[m][n][j] = (isdiag && rowg == colg) ? 0.f : ex;
        }
    // row sums -> slot 4*ct + wc
#pragma unroll
    for (int m = 0; m < 4; ++m)
#pragma unroll
      for (int j = 0; j < 4; ++j) {
        float rs = acc[m][0][j] + acc[m][1][j];
        rs += __shfl_xor(rs, 1);
        rs += __shfl_xor(rs, 2);
        rs += __shfl_xor(rs, 4);
        rs += __shfl_xor(rs, 8);
        if ((lane & 15) == 0) {
          int rowg = rbase + m * 16 + g * 4 + j;
          partial[(size_t)(4 * ct + wc) * N + rowg] = rs;
        }
      }
    // col sums -> slots 4*rt + 2*wr + rowhalf (R6-verified write pattern)
    if (!isdiag) {
#pragma unroll
      for (int n = 0; n < 2; ++n) {
        float cs = 0.f;
#pragma unroll
        for (int m = 0; m < 4; ++m)
#pragma unroll
          for (int j = 0; j < 4; ++j) cs += acc[m][n][j];
        cs += __shfl_xor(cs, 16);      // combine row-groups {0,1} and {2,3}
        if ((g & 1) == 0) {            // lanes 0-15 (half 0), 32-47 (half 1)
          int colg = cbase + n * 16;
          int slot = 4 * rt + 2 * wr + (g >> 1);
          partial[(size_t)slot * N + colg] = cs;
        }
      }
    }

    // advance (uniform)
    ++ct;
    if (ct == TGRID) { ++rt; ct = rt; }
  }
}

// ---------------- kernel 3: per-row finish + per-block sum ----------------
__global__ __launch_bounds__(256) void nt_rowfinish(
    const float* __restrict__ partial, const float* __restrict__ pos,
    float* __restrict__ blocksum, int N, int B) {
  int r = blockIdx.x * 256 + threadIdx.x;
  float s0 = 0.f, s1 = 0.f, s2 = 0.f, s3 = 0.f;
#pragma unroll 4
  for (int p = 0; p < 256; p += 4) {
    s0 += partial[(size_t)p * N + r];
    s1 += partial[(size_t)(p + 1) * N + r];
    s2 += partial[(size_t)(p + 2) * N + r];
    s3 += partial[(size_t)(p + 3) * N + r];
  }
  float s = (s0 + s1) + (s2 + s3);
  float pv = pos[r < B ? r : r - B];
  float lr = logf(s) - pv * (1.0f / TEMP);
  for (int off = 1; off < 64; off <<= 1) lr += __shfl_xor(lr, off);
  __shared__ float red[4];
  int wv = threadIdx.x >> 6, lane = threadIdx.x & 63;
  if (lane == 0) red[wv] = lr;
  __syncthreads();
  if (threadIdx.x == 0)
    blocksum[blockIdx.x] = red[0] + red[1] + red[2] + red[3];
}

// ---------------- kernel 4: final scalar reduce (32 values) ----------------
__global__ __launch_bounds__(64) void nt_final(
    const float* __restrict__ blocksum, float* __restrict__ out, int N) {
  int lane = threadIdx.x;
  float s = (lane < 32) ? blocksum[lane] : 0.f;
  for (int off = 1; off < 32; off <<= 1) s += __shfl_xor(s, off);
  if (lane == 0) out[0] = s / (float)N;
}

extern "C" void kernel_launch(void* const* d_in, const int* in_sizes, int n_in,
                              void* d_out, int out_size, void* d_ws, size_t ws_size,
                              hipStream_t stream) {
  const float* ei = (const float*)d_in[0];
  const float* ej = (const float*)d_in[1];
  int B = in_sizes[0] / D_DIM;  // 4096
  int N = 2 * B;                // 8192

  char* ws = (char*)d_ws;
  unsigned char* z8 = (unsigned char*)ws;                         // N*256 = 2 MB
  float* partial  = (float*)(ws + (size_t)N * D_DIM);             // 256*N*4 = 8 MB
  float* pos      = (float*)(ws + (size_t)N * D_DIM + (size_t)256 * N * 4);
  float* blocksum = pos + B;
  float* out = (float*)d_out;

  nt_normalize<<<B, 256, 0, stream>>>(ei, ej, z8, pos, B);
  nt_gemm_rowsum<<<NBLK, 512, 0, stream>>>(z8, partial, N);
  nt_rowfinish<<<N / 256, 256, 0, stream>>>(partial, pos, blocksum, N, B);
  nt_final<<<1, 64, 0, stream>>>(blocksum, out, N);
}

// Round 9
// 86.302 us; speedup vs baseline: 1.2269x; 1.2269x over previous
//
#include <hip/hip_runtime.h>
#include <hip/hip_bf16.h>

#define D_DIM 256
#define TEMP 0.2f
// ZSCALE = sqrt(log2(e)/TEMP): fold 1/(T*ln2) into z so epilogue is exp2(acc)
#define ZSCALE 2.6857913f
#define TGRID 64           // N / 128 row/col tiles
#define NBLK 512           // 2 resident blocks per CU (VGPR<=128, LDS 2x32KB)
#define NTILES 2080        // TGRID*(TGRID+1)/2 triangular tiles

typedef float f32x4 __attribute__((ext_vector_type(4)));
typedef unsigned long ulong_t;

typedef const __attribute__((address_space(1))) void* gptr_t;
typedef __attribute__((address_space(3))) void* lptr_t;

// ---------------- kernel 1: normalize + positives -> fp8 e4m3 ----------------
__global__ __launch_bounds__(256) void nt_normalize(
    const float* __restrict__ ei, const float* __restrict__ ej,
    unsigned char* __restrict__ z8, float* __restrict__ pos, int B) {
  int b = blockIdx.x;
  int d = threadIdx.x;
  float xi = ei[(size_t)b * D_DIM + d];
  float xj = ej[(size_t)b * D_DIM + d];
  float si = xi * xi, sj = xj * xj, sij = xi * xj;
  for (int off = 1; off < 64; off <<= 1) {
    si  += __shfl_xor(si, off);
    sj  += __shfl_xor(sj, off);
    sij += __shfl_xor(sij, off);
  }
  __shared__ float red[3][4];
  int wv = threadIdx.x >> 6, lane = threadIdx.x & 63;
  if (lane == 0) { red[0][wv] = si; red[1][wv] = sj; red[2][wv] = sij; }
  __syncthreads();
  si  = red[0][0] + red[0][1] + red[0][2] + red[0][3];
  sj  = red[1][0] + red[1][1] + red[1][2] + red[1][3];
  sij = red[2][0] + red[2][1] + red[2][2] + red[2][3];
  float ri = rsqrtf(si), rj = rsqrtf(sj);
  float zif = xi * ri * ZSCALE;
  float zjf = xj * rj * ZSCALE;
  // pack pairs (d, d+1) into one ushort of 2 fp8 bytes (HW RNE, OCP e4m3)
  float zih = __shfl_down(zif, 1);
  float zjh = __shfl_down(zjf, 1);
  if ((d & 1) == 0) {
    int pki = __builtin_amdgcn_cvt_pk_fp8_f32(zif, zih, 0, false);
    int pkj = __builtin_amdgcn_cvt_pk_fp8_f32(zjf, zjh, 0, false);
    ushort* zi_row = (ushort*)(z8 + (size_t)b * D_DIM);
    ushort* zj_row = (ushort*)(z8 + (size_t)(B + b) * D_DIM);
    zi_row[d >> 1] = (ushort)(pki & 0xffff);
    zj_row[d >> 1] = (ushort)(pkj & 0xffff);
  }
  if (threadIdx.x == 0) pos[b] = sij * ri * rj;
}

// ---------------- kernel 2: barrier-free triangular GEMM (fp8) --------------
// 512 threads = 8 waves (2 wave-rows x 4 wave-cols); wave tile 64 rows x 32
// cols. A panel (128 x K=256 fp8) in registers (af[8][4] ulong = 64 VGPR),
// staged via LDS only at rt transitions. B is STREAMED from global
// (L2-resident z8, 2MB) into registers: all 16 global_load_dwordx2 hoisted
// ahead of the MFMA loop (128B in flight covers L2 latency). The ct-sweep has
// NO __syncthreads -- waves free-run; one wave's loads/epilogue overlap other
// waves' MFMA. launch_bounds(512,2): cap 256 regs (R7-verified 104, no
// spill); ~128 used -> 2 blocks/CU co-resident = 16 waves/CU.
// partial slots (256), R6-verified exact partition:
//   row-sums of (rt,ct) -> slot 4*ct+wc;  col-sums (rt<ct) -> 4*rt+2*wr+half.
__global__ __launch_bounds__(512, 2) void nt_gemm_rowsum(
    const unsigned char* __restrict__ z8, float* __restrict__ partial, int N) {
  // XCD-chunked bijective remap: consecutive logical blocks (sharing panels)
  // land on the same XCD's L2.
  int hw = blockIdx.x;
  int b = (hw & 7) * (NBLK / 8) + (hw >> 3);
  int s = (b * NTILES) / NBLK;
  int e = ((b + 1) * NTILES) / NBLK;

  // decode first tile index -> (rt, ct), lex order over ct>=rt
  int rem = s, rt = 0;
  while (rem >= TGRID - rt) { rem -= TGRID - rt; ++rt; }
  int ct = rt + rem;

  __shared__ __align__(16) unsigned char As[128 * 256];  // 32KB A-stage buffer

  int t = threadIdx.x, lane = t & 63, wv = t >> 6;
  int wr = wv >> 2, wc = wv & 3;    // 2 wave-rows x 4 wave-cols
  int g = lane >> 4;                // lane quad 0..3

  // Stage a 128x256 fp8 panel (32KB): 2048 16B chunks, 16 per 256B row.
  // XOR swizzle (byte ^= (row&7)<<4) via inverse-swizzled SOURCE (rule #21).
  auto STAGE = [&](int panel) {
#pragma unroll
    for (int p = 0; p < 4; ++p) {
      int chunk = p * 512 + t;          // 0..2047
      int row = chunk >> 4;             // 16 chunks per 256B row
      int c = chunk & 15;
      int cl = c ^ (row & 7);           // inverse swizzle on SOURCE
      const char* gsrc = (const char*)z8 + (size_t)(panel * 128 + row) * 256 + cl * 16;
      __builtin_amdgcn_global_load_lds((gptr_t)gsrc, (lptr_t)((char*)As + chunk * 16), 16, 0, 0);
    }
  };

  ulong_t af[8][4];                     // A frags [ks][m]: 64 rows x K=256
  auto READ_AF = [&]() {
#pragma unroll
    for (int ks = 0; ks < 8; ++ks)
#pragma unroll
      for (int m = 0; m < 4; ++m) {
        int r = wr * 64 + m * 16 + (lane & 15);
        int addr = ((r << 8) + ks * 32 + (g << 3)) ^ ((r & 7) << 4);
        af[ks][m] = *reinterpret_cast<const ulong_t*>((const char*)As + addr);
      }
  };

  int cur_rt = -1;

  for (int idx = s; idx < e; ++idx) {
    if (rt != cur_rt) {                 // uniform across the block
      __syncthreads();                  // everyone done with previous A buffer
      STAGE(rt);
      __syncthreads();                  // vmcnt drained: panel in LDS
      READ_AF();
      cur_rt = rt;
    }

    // ---- B stream: hoist all 16 loads (independent, 128B in flight) ----
    const unsigned char* b0 =
        z8 + (((size_t)(ct * 128 + wc * 32 + (lane & 15))) << 8) + (g << 3);
    const unsigned char* b1 = b0 + (16 << 8);   // +16 rows
    ulong_t bl0[8], bl1[8];
#pragma unroll
    for (int ks = 0; ks < 8; ++ks) {
      bl0[ks] = *reinterpret_cast<const ulong_t*>(b0 + ks * 32);
      bl1[ks] = *reinterpret_cast<const ulong_t*>(b1 + ks * 32);
    }

    // ---- compute: acc = A_regs x B_regs over K=256 ----
    f32x4 acc[4][2];
#pragma unroll
    for (int m = 0; m < 4; ++m)
#pragma unroll
      for (int n = 0; n < 2; ++n) acc[m][n] = f32x4{0.f, 0.f, 0.f, 0.f};
#pragma unroll
    for (int ks = 0; ks < 8; ++ks) {
#pragma unroll
      for (int m = 0; m < 4; ++m) {
        acc[m][0] = __builtin_amdgcn_mfma_f32_16x16x32_fp8_fp8(
            (long)af[ks][m], (long)bl0[ks], acc[m][0], 0, 0, 0);
        acc[m][1] = __builtin_amdgcn_mfma_f32_16x16x32_fp8_fp8(
            (long)af[ks][m], (long)bl1[ks], acc[m][1], 0, 0, 0);
      }
    }

    // ---- epilogue (register-only): exp2, diag mask, row/col sums ----
    bool isdiag = (rt == ct);
    int rbase = rt * 128 + wr * 64;
    int cbase = ct * 128 + wc * 32 + (lane & 15);
#pragma unroll
    for (int m = 0; m < 4; ++m)
#pragma unroll
      for (int n = 0; n < 2; ++n)
#pragma unroll
        for (int j = 0; j < 4; ++j) {
          int rowg = rbase + m * 16 + g * 4 + j;
          int colg = cbase + n * 16;
          float ex = exp2f(acc[m][n][j]);
          acc[m][n][j] = (isdiag && rowg == colg) ? 0.f : ex;
        }
    // row sums -> slot 4*ct + wc
#pragma unroll
    for (int m = 0; m < 4; ++m)
#pragma unroll
      for (int j = 0; j < 4; ++j) {
        float rs = acc[m][0][j] + acc[m][1][j];
        rs += __shfl_xor(rs, 1);
        rs += __shfl_xor(rs, 2);
        rs += __shfl_xor(rs, 4);
        rs += __shfl_xor(rs, 8);
        if ((lane & 15) == 0) {
          int rowg = rbase + m * 16 + g * 4 + j;
          partial[(size_t)(4 * ct + wc) * N + rowg] = rs;
        }
      }
    // col sums -> slots 4*rt + 2*wr + rowhalf (R6-verified write pattern)
    if (!isdiag) {
#pragma unroll
      for (int n = 0; n < 2; ++n) {
        float cs = 0.f;
#pragma unroll
        for (int m = 0; m < 4; ++m)
#pragma unroll
          for (int j = 0; j < 4; ++j) cs += acc[m][n][j];
        cs += __shfl_xor(cs, 16);      // combine row-groups {0,1} and {2,3}
        if ((g & 1) == 0) {            // lanes 0-15 (half 0), 32-47 (half 1)
          int colg = cbase + n * 16;
          int slot = 4 * rt + 2 * wr + (g >> 1);
          partial[(size_t)slot * N + colg] = cs;
        }
      }
    }

    // advance (uniform)
    ++ct;
    if (ct == TGRID) { ++rt; ct = rt; }
  }
}

// ---------------- kernel 3: per-row finish + per-block sum ----------------
__global__ __launch_bounds__(256) void nt_rowfinish(
    const float* __restrict__ partial, const float* __restrict__ pos,
    float* __restrict__ blocksum, int N, int B) {
  int r = blockIdx.x * 256 + threadIdx.x;
  float s0 = 0.f, s1 = 0.f, s2 = 0.f, s3 = 0.f;
#pragma unroll 4
  for (int p = 0; p < 256; p += 4) {
    s0 += partial[(size_t)p * N + r];
    s1 += partial[(size_t)(p + 1) * N + r];
    s2 += partial[(size_t)(p + 2) * N + r];
    s3 += partial[(size_t)(p + 3) * N + r];
  }
  float s = (s0 + s1) + (s2 + s3);
  float pv = pos[r < B ? r : r - B];
  float lr = logf(s) - pv * (1.0f / TEMP);
  for (int off = 1; off < 64; off <<= 1) lr += __shfl_xor(lr, off);
  __shared__ float red[4];
  int wv = threadIdx.x >> 6, lane = threadIdx.x & 63;
  if (lane == 0) red[wv] = lr;
  __syncthreads();
  if (threadIdx.x == 0)
    blocksum[blockIdx.x] = red[0] + red[1] + red[2] + red[3];
}

// ---------------- kernel 4: final scalar reduce (32 values) ----------------
__global__ __launch_bounds__(64) void nt_final(
    const float* __restrict__ blocksum, float* __restrict__ out, int N) {
  int lane = threadIdx.x;
  float s = (lane < 32) ? blocksum[lane] : 0.f;
  for (int off = 1; off < 32; off <<= 1) s += __shfl_xor(s, off);
  if (lane == 0) out[0] = s / (float)N;
}

extern "C" void kernel_launch(void* const* d_in, const int* in_sizes, int n_in,
                              void* d_out, int out_size, void* d_ws, size_t ws_size,
                              hipStream_t stream) {
  const float* ei = (const float*)d_in[0];
  const float* ej = (const float*)d_in[1];
  int B = in_sizes[0] / D_DIM;  // 4096
  int N = 2 * B;                // 8192

  char* ws = (char*)d_ws;
  unsigned char* z8 = (unsigned char*)ws;                         // N*256 = 2 MB
  float* partial  = (float*)(ws + (size_t)N * D_DIM);             // 256*N*4 = 8 MB
  float* pos      = (float*)(ws + (size_t)N * D_DIM + (size_t)256 * N * 4);
  float* blocksum = pos + B;
  float* out = (float*)d_out;

  nt_normalize<<<B, 256, 0, stream>>>(ei, ej, z8, pos, B);
  nt_gemm_rowsum<<<NBLK, 512, 0, stream>>>(z8, partial, N);
  nt_rowfinish<<<N / 256, 256, 0, stream>>>(partial, pos, blocksum, N, B);
  nt_final<<<1, 64, 0, stream>>>(blocksum, out, N);
}

// Round 10
// 67.391 us; speedup vs baseline: 1.5711x; 1.2806x over previous
//
#include <hip/hip_runtime.h>
#include <hip/hip_bf16.h>

#define D_DIM 256
#define TEMP 0.2f
// ZSCALE = sqrt(log2(e)/TEMP): fold 1/(T*ln2) into z so epilogue is exp2(acc)
#define ZSCALE 2.6857913f
#define TGRID 64           // N / 128 row/col tiles
#define NBLK 256           // 1 block per CU (512 thr); pipeline needs no co-residency
#define NTILES 2080        // TGRID*(TGRID+1)/2 triangular tiles

typedef float f32x4 __attribute__((ext_vector_type(4)));
typedef unsigned long ulong_t;

typedef const __attribute__((address_space(1))) void* gptr_t;
typedef __attribute__((address_space(3))) void* lptr_t;

// ---------------- kernel 1: normalize + positives -> fp8 e4m3 ----------------
__global__ __launch_bounds__(256) void nt_normalize(
    const float* __restrict__ ei, const float* __restrict__ ej,
    unsigned char* __restrict__ z8, float* __restrict__ pos, int B) {
  int b = blockIdx.x;
  int d = threadIdx.x;
  float xi = ei[(size_t)b * D_DIM + d];
  float xj = ej[(size_t)b * D_DIM + d];
  float si = xi * xi, sj = xj * xj, sij = xi * xj;
  for (int off = 1; off < 64; off <<= 1) {
    si  += __shfl_xor(si, off);
    sj  += __shfl_xor(sj, off);
    sij += __shfl_xor(sij, off);
  }
  __shared__ float red[3][4];
  int wv = threadIdx.x >> 6, lane = threadIdx.x & 63;
  if (lane == 0) { red[0][wv] = si; red[1][wv] = sj; red[2][wv] = sij; }
  __syncthreads();
  si  = red[0][0] + red[0][1] + red[0][2] + red[0][3];
  sj  = red[1][0] + red[1][1] + red[1][2] + red[1][3];
  sij = red[2][0] + red[2][1] + red[2][2] + red[2][3];
  float ri = rsqrtf(si), rj = rsqrtf(sj);
  float zif = xi * ri * ZSCALE;
  float zjf = xj * rj * ZSCALE;
  // pack pairs (d, d+1) into one ushort of 2 fp8 bytes (HW RNE, OCP e4m3)
  float zih = __shfl_down(zif, 1);
  float zjh = __shfl_down(zjf, 1);
  if ((d & 1) == 0) {
    int pki = __builtin_amdgcn_cvt_pk_fp8_f32(zif, zih, 0, false);
    int pkj = __builtin_amdgcn_cvt_pk_fp8_f32(zjf, zjh, 0, false);
    ushort* zi_row = (ushort*)(z8 + (size_t)b * D_DIM);
    ushort* zj_row = (ushort*)(z8 + (size_t)(B + b) * D_DIM);
    zi_row[d >> 1] = (ushort)(pki & 0xffff);
    zj_row[d >> 1] = (ushort)(pkj & 0xffff);
  }
  if (threadIdx.x == 0) pos[b] = sij * ri * rj;
}

// ---------------- kernel 2: counted-vmcnt pipelined triangular GEMM (fp8) ---
// 512 threads = 8 waves (2 wave-rows x 4 wave-cols); wave tile 64x32.
// A panel (128 x K=256 fp8) in registers (af[8][4] ulong = 64 VGPR); B
// double-buffered in LDS (2 x 32KB), staged with coalesced global_load_lds.
// Pipeline (T4): per tile, per-wave VMEM issue order is
//   stage(i)[4] ... stores(i-1)[<=18] ... stage(i+1)[4]
// and vmcnt retires IN ORDER, so `s_waitcnt vmcnt(16)` + one raw s_barrier
// guarantees stage(i) landed for ALL waves while stores + stage(i+1) stay in
// flight across the barrier. No vmcnt(0) drain in the loop. Prologue drains
// once so the steady-state count is uniform.
// At each row transition the diagonal tile's B panel IS the new A panel ->
// READ_AF from the current buffer (no extra staging).
// XOR swizzle (byte ^= (row&7)<<4) on the 16B-chunk index of the global
// SOURCE (linear LDS dest, rule #21) and on every ds_read address.
// partial slots (256), R6-verified exact partition:
//   row-sums of (rt,ct) -> slot 4*ct+wc;  col-sums (rt<ct) -> 4*rt+2*wr+half.
__global__ __launch_bounds__(512, 2) void nt_gemm_rowsum(
    const unsigned char* __restrict__ z8, float* __restrict__ partial, int N) {
  // XCD-chunked bijective remap (NBLK%8==0)
  int hw = blockIdx.x;
  int b = (hw & 7) * (NBLK / 8) + (hw >> 3);
  int s = (b * NTILES) / NBLK;
  int e = ((b + 1) * NTILES) / NBLK;

  // decode first tile index -> (rt, ct), lex order over ct>=rt
  int rem = s, rt = 0;
  while (rem >= TGRID - rt) { rem -= TGRID - rt; ++rt; }
  int ct = rt + rem;

  __shared__ __align__(16) unsigned char Bs[2][128 * 256];  // 2 x 32KB

  int t = threadIdx.x, lane = t & 63, wv = t >> 6;
  int wr = wv >> 2, wc = wv & 3;    // 2 wave-rows x 4 wave-cols
  int g = lane >> 4;                // lane quad 0..3

  // Stage a 128x256 fp8 panel (32KB): 2048 16B chunks, 16 per 256B row.
  auto STAGE = [&](int buf, int panel) {
#pragma unroll
    for (int p = 0; p < 4; ++p) {
      int chunk = p * 512 + t;          // 0..2047
      int row = chunk >> 4;             // 16 chunks per 256B row
      int c = chunk & 15;
      int cl = c ^ (row & 7);           // inverse swizzle on SOURCE
      const char* gsrc = (const char*)z8 + (size_t)(panel * 128 + row) * 256 + cl * 16;
      __builtin_amdgcn_global_load_lds((gptr_t)gsrc,
                                       (lptr_t)((char*)Bs[buf] + chunk * 16), 16, 0, 0);
    }
  };

  ulong_t af[8][4];                     // A frags [ks][m]: 64 rows x K=256
  auto READ_AF = [&](int buf) {
    const char* src = (const char*)Bs[buf];
#pragma unroll
    for (int ks = 0; ks < 8; ++ks)
#pragma unroll
      for (int m = 0; m < 4; ++m) {
        int r = wr * 64 + m * 16 + (lane & 15);
        int addr = ((r << 8) + ks * 32 + (g << 3)) ^ ((r & 7) << 4);
        af[ks][m] = *reinterpret_cast<const ulong_t*>(src + addr);
      }
  };

  // ---- prologue: panel(s) into buf0, af ready, all drained ----
  int bp = 0;
  if (ct == rt) {
    STAGE(0, rt);
    __syncthreads();                    // drain; READ_AF happens in-loop
  } else {
    STAGE(0, rt);                       // A panel first
    __syncthreads();
    READ_AF(0);
    __syncthreads();                    // af reads done before overwrite
    STAGE(0, ct);                       // first B panel
    __syncthreads();                    // drain -> loop steady state
  }

  for (int idx = s; idx < e; ++idx) {
    // stage(idx) guaranteed complete (in-order vmcnt; <=16 newer ops float)
    asm volatile("s_waitcnt vmcnt(16)" ::: "memory");
    __builtin_amdgcn_s_barrier();       // all waves agree: buf[bp] ready,
                                        // buf[bp^1] free (its readers passed)
    __builtin_amdgcn_sched_barrier(0);

    bool lastrow = (ct == TGRID - 1);
    if (idx + 1 < e) STAGE(bp ^ 1, lastrow ? (rt + 1) : (ct + 1));

    if (ct == rt) READ_AF(bp);          // diagonal tile: B panel == A panel

    // ---- compute: acc = A_regs x B_lds over K=256 ----
    f32x4 acc[4][2];
#pragma unroll
    for (int m = 0; m < 4; ++m)
#pragma unroll
      for (int n = 0; n < 2; ++n) acc[m][n] = f32x4{0.f, 0.f, 0.f, 0.f};
    const char* cb = (const char*)Bs[bp];
#pragma unroll
    for (int ks = 0; ks < 8; ++ks) {
      ulong_t bf0, bf1;
      {
        int r = wc * 32 + (lane & 15);
        int addr = ((r << 8) + ks * 32 + (g << 3)) ^ ((r & 7) << 4);
        bf0 = *reinterpret_cast<const ulong_t*>(cb + addr);
        int r1 = r + 16;
        int addr1 = ((r1 << 8) + ks * 32 + (g << 3)) ^ ((r1 & 7) << 4);
        bf1 = *reinterpret_cast<const ulong_t*>(cb + addr1);
      }
#pragma unroll
      for (int m = 0; m < 4; ++m) {
        acc[m][0] = __builtin_amdgcn_mfma_f32_16x16x32_fp8_fp8(
            (long)af[ks][m], (long)bf0, acc[m][0], 0, 0, 0);
        acc[m][1] = __builtin_amdgcn_mfma_f32_16x16x32_fp8_fp8(
            (long)af[ks][m], (long)bf1, acc[m][1], 0, 0, 0);
      }
    }

    // ---- epilogue (register-only): exp2, diag mask, row/col sums ----
    bool isdiag = (rt == ct);
    int rbase = rt * 128 + wr * 64;
    int cbase = ct * 128 + wc * 32 + (lane & 15);
#pragma unroll
    for (int m = 0; m < 4; ++m)
#pragma unroll
      for (int n = 0; n < 2; ++n)
#pragma unroll
        for (int j = 0; j < 4; ++j) {
          int rowg = rbase + m * 16 + g * 4 + j;
          int colg = cbase + n * 16;
          float ex = exp2f(acc[m][n][j]);
          acc[m][n][j] = (isdiag && rowg == colg) ? 0.f : ex;
        }
    // row sums -> slot 4*ct + wc   (16 stores/wave)
#pragma unroll
    for (int m = 0; m < 4; ++m)
#pragma unroll
      for (int j = 0; j < 4; ++j) {
        float rs = acc[m][0][j] + acc[m][1][j];
        rs += __shfl_xor(rs, 1);
        rs += __shfl_xor(rs, 2);
        rs += __shfl_xor(rs, 4);
        rs += __shfl_xor(rs, 8);
        if ((lane & 15) == 0) {
          int rowg = rbase + m * 16 + g * 4 + j;
          partial[(size_t)(4 * ct + wc) * N + rowg] = rs;
        }
      }
    // col sums -> slots 4*rt + 2*wr + rowhalf   (2 stores/wave)
    if (!isdiag) {
#pragma unroll
      for (int n = 0; n < 2; ++n) {
        float cs = 0.f;
#pragma unroll
        for (int m = 0; m < 4; ++m)
#pragma unroll
          for (int j = 0; j < 4; ++j) cs += acc[m][n][j];
        cs += __shfl_xor(cs, 16);      // combine row-groups {0,1} and {2,3}
        if ((g & 1) == 0) {            // lanes 0-15 (half 0), 32-47 (half 1)
          int colg = cbase + n * 16;
          int slot = 4 * rt + 2 * wr + (g >> 1);
          partial[(size_t)slot * N + colg] = cs;
        }
      }
    }

    // advance (uniform)
    ++ct;
    if (ct == TGRID) { ++rt; ct = rt; }
    bp ^= 1;
  }
}

// ---------------- kernel 3: per-row finish + per-block sum ----------------
__global__ __launch_bounds__(256) void nt_rowfinish(
    const float* __restrict__ partial, const float* __restrict__ pos,
    float* __restrict__ blocksum, int N, int B) {
  int r = blockIdx.x * 256 + threadIdx.x;
  float s0 = 0.f, s1 = 0.f, s2 = 0.f, s3 = 0.f;
#pragma unroll 4
  for (int p = 0; p < 256; p += 4) {
    s0 += partial[(size_t)p * N + r];
    s1 += partial[(size_t)(p + 1) * N + r];
    s2 += partial[(size_t)(p + 2) * N + r];
    s3 += partial[(size_t)(p + 3) * N + r];
  }
  float s = (s0 + s1) + (s2 + s3);
  float pv = pos[r < B ? r : r - B];
  float lr = logf(s) - pv * (1.0f / TEMP);
  for (int off = 1; off < 64; off <<= 1) lr += __shfl_xor(lr, off);
  __shared__ float red[4];
  int wv = threadIdx.x >> 6, lane = threadIdx.x & 63;
  if (lane == 0) red[wv] = lr;
  __syncthreads();
  if (threadIdx.x == 0)
    blocksum[blockIdx.x] = red[0] + red[1] + red[2] + red[3];
}

// ---------------- kernel 4: final scalar reduce (32 values) ----------------
__global__ __launch_bounds__(64) void nt_final(
    const float* __restrict__ blocksum, float* __restrict__ out, int N) {
  int lane = threadIdx.x;
  float s = (lane < 32) ? blocksum[lane] : 0.f;
  for (int off = 1; off < 32; off <<= 1) s += __shfl_xor(s, off);
  if (lane == 0) out[0] = s / (float)N;
}

extern "C" void kernel_launch(void* const* d_in, const int* in_sizes, int n_in,
                              void* d_out, int out_size, void* d_ws, size_t ws_size,
                              hipStream_t stream) {
  const float* ei = (const float*)d_in[0];
  const float* ej = (const float*)d_in[1];
  int B = in_sizes[0] / D_DIM;  // 4096
  int N = 2 * B;                // 8192

  char* ws = (char*)d_ws;
  unsigned char* z8 = (unsigned char*)ws;                         // N*256 = 2 MB
  float* partial  = (float*)(ws + (size_t)N * D_DIM);             // 256*N*4 = 8 MB
  float* pos      = (float*)(ws + (size_t)N * D_DIM + (size_t)256 * N * 4);
  float* blocksum = pos + B;
  float* out = (float*)d_out;

  nt_normalize<<<B, 256, 0, stream>>>(ei, ej, z8, pos, B);
  nt_gemm_rowsum<<<NBLK, 512, 0, stream>>>(z8, partial, N);
  nt_rowfinish<<<N / 256, 256, 0, stream>>>(partial, pos, blocksum, N, B);
  nt_final<<<1, 64, 0, stream>>>(blocksum, out, N);
}